// Round 10
// baseline (10788.286 us; speedup 1.0000x reference)
//
#include <hip/hip_runtime.h>

// Problem constants
#define B_    64
#define C_    4096
#define T_ALL 72
#define T_H   24
#define T_FC  48
#define F_IN  8
#define HID   64
#define NSEQ  (B_ * C_)   // 262144

typedef float f32x4 __attribute__((ext_vector_type(4)));

// ---------------------------------------------------------------------------
// Setup: fold fc_in into W_ih.
//   Wc[j][i] = sum_k W_ih[j][k] * W_in[k][i]   (192 x 4)
//   bc[j]    = b_ih[j] + sum_k W_ih[j][k] * b_in[k]
// ws layout: [0..767] Wc row-major, [768..959] bc
// ---------------------------------------------------------------------------
__global__ __launch_bounds__(192) void setup_kernel(
    const float* __restrict__ W_in, const float* __restrict__ b_in,
    const float* __restrict__ W_ih, const float* __restrict__ b_ih,
    float* __restrict__ ws) {
  int j = threadIdx.x;  // 0..191
  float a0 = 0.f, a1 = 0.f, a2 = 0.f, a3 = 0.f, ab = 0.f;
  for (int k = 0; k < HID; ++k) {
    float w = W_ih[j * HID + k];
    a0 += w * W_in[k * 4 + 0];
    a1 += w * W_in[k * 4 + 1];
    a2 += w * W_in[k * 4 + 2];
    a3 += w * W_in[k * 4 + 3];
    ab += w * b_in[k];
  }
  ws[j * 4 + 0] = a0;
  ws[j * 4 + 1] = a1;
  ws[j * 4 + 2] = a2;
  ws[j * 4 + 3] = a3;
  ws[768 + j] = ab + b_ih[j];
}

// Fast activations: single v_exp_f32 + v_rcp_f32 (~1 ulp, fine vs tol)
__device__ __forceinline__ float fast_sigmoid(float x) {
  float e = __builtin_amdgcn_exp2f(-1.4426950408889634f * x);
  return __builtin_amdgcn_rcpf(1.0f + e);
}
// tanh(x) = 2*sigmoid(2x) - 1  (no overflow/NaN at large |x|)
__device__ __forceinline__ float fast_tanh(float x) {
  float e = __builtin_amdgcn_exp2f(-2.8853900817779268f * x);
  return 2.0f * __builtin_amdgcn_rcpf(1.0f + e) - 1.0f;
}

#define REP16(M) M(0) M(1) M(2) M(3) M(4) M(5) M(6) M(7) \
                 M(8) M(9) M(10) M(11) M(12) M(13) M(14) M(15)

// Register pin: makes the value opaque so the compiler cannot re-sink the
// originating load into the loop (round-4 failure mode: VGPR_Count=124 with
// 192 weight floats "hoisted" -> loads sunk, W_hh re-fetched from L2 every
// step = 415 GB of L2 traffic, L2-BW-bound at 9.5 ms).
#define PIN(x) asm volatile("" : "+v"(x))

// ---------------------------------------------------------------------------
// Wave-per-sequence, lane-per-hidden-unit GRU.
// Lane u owns hidden unit u: scalar state h, 3 W_hh rows in 48 PINNED f32x4
// registers. h exchanged via per-wave 64-float LDS slot (write: 2 lanes/bank
// = free; reads: lane-uniform broadcast = conflict-free). Wave-uniform values
// (seq id, X pointer, x inputs, xp feedback) live in SGPRs.
//
// ROUND-9 FIX: xp feedback used __builtin_amdgcn_readfirstlane(float) which
// implicitly converts float->int (TRUNCATION) -> absmax 7.2e-2. Now bit-cast
// through uint for a bit-exact uniform broadcast.
// ---------------------------------------------------------------------------
__global__ __launch_bounds__(256, 2) void gru_kernel(
    const float* __restrict__ X, const float* __restrict__ H,
    const float* __restrict__ xn, const float* __restrict__ W_hh,
    const float* __restrict__ b_hh, const float* __restrict__ W_out,
    const float* __restrict__ b_out, const float* __restrict__ ws,
    float* __restrict__ out) {
  __shared__ float sH[4 * HID];  // 4 waves/block, 64 floats each

  const int tid  = threadIdx.x;
  const int lane = tid & 63;
  const int wid  = __builtin_amdgcn_readfirstlane(tid >> 6);  // wave-uniform
  const int s = blockIdx.x * 4 + wid;  // sequence id = b*C + c (SGPR)
  const int b = s >> 12;               // / 4096
  const int c = s & 4095;

  // Per-lane W_hh rows (u, 64+u, 128+u). One-time fetch (L2-resident 48 KB),
  // then pinned into registers for all 48 steps.
  const f32x4* Wr4 = reinterpret_cast<const f32x4*>(W_hh + lane * HID);
  const f32x4* Wz4 = reinterpret_cast<const f32x4*>(W_hh + (64 + lane) * HID);
  const f32x4* Wn4 = reinterpret_cast<const f32x4*>(W_hh + (128 + lane) * HID);
#define LOADW(i) f32x4 wr##i = Wr4[i]; f32x4 wz##i = Wz4[i]; f32x4 wn##i = Wn4[i];
  REP16(LOADW)
#undef LOADW
#define PINW(i) PIN(wr##i); PIN(wz##i); PIN(wn##i);
  REP16(PINW)
#undef PINW

  // Fused input weights/biases, per lane (pinned too).
  const f32x4* Wc4 = reinterpret_cast<const f32x4*>(ws);
  f32x4 wcr = Wc4[lane];
  f32x4 wcz = Wc4[64 + lane];
  f32x4 wcn = Wc4[128 + lane];
  PIN(wcr); PIN(wcz); PIN(wcn);
  // r/z: input bias + recurrent bias merged. n: kept apart (recurrent part is
  // multiplied by r before adding the input part).
  float br  = ws[768 + lane] + b_hh[lane];
  float bz  = ws[832 + lane] + b_hh[64 + lane];
  float bcn = ws[896 + lane];
  float bhn = b_hh[128 + lane];
  float wo  = W_out[lane];
  PIN(br); PIN(bz); PIN(bcn); PIN(bhn); PIN(wo);
  const float bo = b_out[0];  // uniform -> SGPR

  float h = H[(size_t)s * HID + lane];  // coalesced 256B/wave

  // Wave-uniform pointers -> SGPR arithmetic; x loads become s_load.
  const float* Xp = X + (((size_t)b * T_ALL + T_H) * C_ + c) * F_IN + 5;
  float* Op = out + (size_t)b * (T_FC * C_) + c;

  float* mysH = sH + wid * HID;
  const f32x4* mysH4 = reinterpret_cast<const f32x4*>(mysH);

  float xp = xn[s];   // uniform
  float x1 = Xp[0];
  float x2 = Xp[1];
  float x3 = Xp[2];

  // Publish initial h (wave-private slot; in-order DS pipe, no barrier).
  mysH[lane] = h;

#pragma unroll 1
  for (int t = 0; t < T_FC; ++t) {
    // Prefetch next step's exogenous inputs (uniform loads; latency hides
    // under the ~500-cycle step body).
    const float* Xn = Xp + ((t < T_FC - 1) ? (C_ * F_IN) : 0);
    const float p1 = Xn[0];
    const float p2 = Xn[1];
    const float p3 = Xn[2];

    float gr = br, gz = bz, gn = bhn;
#define DOT(i) { const f32x4 hv = mysH4[i];                                    \
    gr += hv.x * wr##i.x + hv.y * wr##i.y + hv.z * wr##i.z + hv.w * wr##i.w;   \
    gz += hv.x * wz##i.x + hv.y * wz##i.y + hv.z * wz##i.z + hv.w * wz##i.w;   \
    gn += hv.x * wn##i.x + hv.y * wn##i.y + hv.z * wn##i.z + hv.w * wn##i.w; }
    REP16(DOT)
#undef DOT

    // Input contributions (uniform xp/x1..x3 * VGPR weights).
    gr += xp * wcr.x + x1 * wcr.y + x2 * wcr.z + x3 * wcr.w;
    gz += xp * wcz.x + x1 * wcz.y + x2 * wcz.z + x3 * wcz.w;
    float in_ = bcn + xp * wcn.x + x1 * wcn.y + x2 * wcn.z + x3 * wcn.w;

    const float r = fast_sigmoid(gr);
    const float z = fast_sigmoid(gz);
    const float n = fast_tanh(in_ + r * gn);
    h = (1.0f - z) * n + z * h;

    // Publish h for next step NOW; the butterfly below covers the DS write
    // latency (in-order DS pipe orders write before next iteration's reads).
    mysH[lane] = h;

    // o = sum_u h_u * Wo_u + bo  — butterfly leaves the sum in ALL lanes.
    float po = h * wo;
    po += __shfl_xor(po, 1, 64);
    po += __shfl_xor(po, 2, 64);
    po += __shfl_xor(po, 4, 64);
    po += __shfl_xor(po, 8, 64);
    po += __shfl_xor(po, 16, 64);
    po += __shfl_xor(po, 32, 64);
    const float o = po + bo;

    if (lane == 0) *Op = o;
    Op += C_;
    // Bit-exact uniform broadcast to SGPR (NOT the int-converting overload).
    xp = __uint_as_float(__builtin_amdgcn_readfirstlane(__float_as_uint(o)));
    x1 = p1;
    x2 = p2;
    x3 = p3;
    Xp = Xn;
  }
}

extern "C" void kernel_launch(void* const* d_in, const int* in_sizes, int n_in,
                              void* d_out, int out_size, void* d_ws,
                              size_t ws_size, hipStream_t stream) {
  const float* X     = (const float*)d_in[0];
  const float* H     = (const float*)d_in[1];
  const float* xn    = (const float*)d_in[2];
  const float* W_in  = (const float*)d_in[3];
  const float* b_in  = (const float*)d_in[4];
  const float* W_ih  = (const float*)d_in[5];
  const float* W_hh  = (const float*)d_in[6];
  const float* b_ih  = (const float*)d_in[7];
  const float* b_hh  = (const float*)d_in[8];
  const float* W_out = (const float*)d_in[9];
  const float* b_out = (const float*)d_in[10];
  float* out = (float*)d_out;
  float* ws  = (float*)d_ws;

  setup_kernel<<<1, 192, 0, stream>>>(W_in, b_in, W_ih, b_ih, ws);
  // One wave per sequence, 4 waves (4 sequences) per 256-thread block.
  gru_kernel<<<NSEQ / 4, 256, 0, stream>>>(X, H, xn, W_hh, b_hh, W_out,
                                           b_out, ws, out);
}